// Round 2
// 71.182 us; speedup vs baseline: 1.0098x; 1.0098x over previous
//
#include <hip/hip_runtime.h>
#include <math.h>

#define N_IMG 512
#define N_ANGLES 25
#define N_DET 512
#define DET_SPACING 3.0f
#define SRC_DIST 512.0f
#define DET_DIST 512.0f
#define N_SAMPLES 1024
#define PAD 8
#define QW 528            // padded grid side: r,c in [-8, 519]

// ---------------------------------------------------------------------------
// ws: 2.23 MB zero-padded VERTICAL-PAIR array (fits the 4 MB per-XCD L2,
// unlike the previous 4.46 MB float4 quad array -> removes L2 capacity
// misses to Infinity Cache, which the R0 counter arithmetic says was the
// remaining ~20 us of the fanbeam kernel).
//   vp[R*QW + C] = { v(r,c), v(r+1,c) },  r=R-PAD, c=C-PAD, v=img inside, 0 out.
//   A bilinear sample at (r0,c0) reads vp[off] and vp[off+1]: ONE address
//   computation, second load folds to `offset:8`.  Arithmetic on the four
//   corners is identical to the previous kernel -> absmax unchanged.
//   off = (int)fmaf(rf, 528.f, cf) is exact in fp32 (values < 2^24).
// ---------------------------------------------------------------------------

__device__ __forceinline__ float img_at(const float* __restrict__ img, int r, int c) {
    return ((unsigned)r < N_IMG && (unsigned)c < N_IMG) ? img[(r << 9) + c] : 0.0f;
}

__global__ __launch_bounds__(256) void build_vpairs(const float* __restrict__ img,
                                                    float2* __restrict__ vp) {
    int idx = blockIdx.x * 256 + (int)threadIdx.x;
    if (idx >= QW * QW) return;
    int R = idx / QW, C = idx - R * QW;
    int r = R - PAD, c = C - PAD;
    float2 q;
    q.x = img_at(img, r,     c);
    q.y = img_at(img, r + 1, c);
    vp[idx] = q;
}

// Clip [tlo,thi] to { t : lo <= v0 + t*dv <= hi }.
__device__ __forceinline__ void slab(float v0, float dv, float lo, float hi,
                                     float& tlo, float& thi) {
    if (fabsf(dv) < 1e-8f) {
        if (v0 < lo || v0 > hi) { tlo = 1.0f; thi = 0.0f; }
    } else {
        float inv = 1.0f / dv;
        float ta = (lo - v0) * inv;
        float tb = (hi - v0) * inv;
        tlo = fmaxf(tlo, fminf(ta, tb));
        thi = fminf(thi, fmaxf(ta, tb));
    }
}

__device__ __forceinline__ float bil2(float2 L, float2 Rr, float fc, float fr) {
    float top = fmaf(fc, Rr.x - L.x, L.x);   // row r0  : v00 + fc*(v01-v00)
    float bot = fmaf(fc, Rr.y - L.y, L.y);   // row r0+1: v10 + fc*(v11-v10)
    return fmaf(fr, bot - top, top);
}

// One wave per ray; 4-deep batched loads; clamp-free padded inner loop.
__global__ __launch_bounds__(256) void fanbeam_kernel(const float2* __restrict__ vp,
                                                      float* __restrict__ out) {
    const int gid  = blockIdx.x * 256 + (int)threadIdx.x;
    const int ray  = gid >> 6;
    const int lane = (int)threadIdx.x & 63;
    if (ray >= N_ANGLES * N_DET) return;

    const int a = ray >> 9;
    const int d = ray & 511;

    float beta = (2.0f * (float)a / 25.0f) * 3.14159265358979323846f;
    float c, s;
    __sincosf(beta, &s, &c);
    float t = ((float)d - (N_DET - 1) * 0.5f) * DET_SPACING;
    float srcx = -SRC_DIST * s;
    float srcy =  SRC_DIST * c;
    float dx = (t * c + DET_DIST * s) - srcx;
    float dy = (t * s - DET_DIST * c) - srcy;
    float seg = sqrtf(dx * dx + dy * dy);

    const float half = (N_IMG - 1) * 0.5f;
    const float col0 = srcx + half;            // unpadded (for clipping)
    const float row0 = half - srcy;
    const float drow = -dy;
    const float col0p = col0 + (float)PAD;     // padded-coordinate origins
    const float row0p = row0 + (float)PAD;
    const float inv_n = 1.0f / N_SAMPLES;

    float tA = 0.0f, tB = 1.0f;
    slab(col0, dx,   -1.01f, 512.01f, tA, tB);
    slab(row0, drow, -1.01f, 512.01f, tA, tB);

    float acc = 0.0f;
    if (tA <= tB) {
        int i_lo = max(0,             (int)floorf(tA * N_SAMPLES - 0.5f) - 1);
        int i_hi = min(N_SAMPLES - 1, (int)ceilf (tB * N_SAMPLES - 0.5f) + 1);
        int n = i_hi - i_lo + 1;                       // wave-uniform
        int k = 0;
        // 4-deep batches: 8 independent dwordx2 loads in flight; padded coords
        // are always >= ~4 within the window, so trunc == floor and no clamps.
        for (; k + 256 <= n; k += 256) {
            float f0 = (float)(i_lo + k + lane);       // exact in fp32
            float acc4 = 0.0f;
            #pragma unroll
            for (int j = 0; j < 4; ++j) {
                float ts  = (f0 + (64.0f * j + 0.5f)) * inv_n;
                float col = fmaf(ts, dx,   col0p);
                float row = fmaf(ts, drow, row0p);
                float cf = floorf(col), rf = floorf(row);
                float fc = col - cf,    fr = row - rf;
                unsigned off = (unsigned)(int)fmaf(rf, (float)QW, cf);
                float2 L  = vp[off];
                float2 Rr = vp[off + 1];
                acc4 += bil2(L, Rr, fc, fr);
            }
            acc += acc4;
        }
        // Tail (< 4 strides): plain loop, still clamp-free.
        #pragma unroll 2
        for (int i = i_lo + k + lane; i <= i_hi; i += 64) {
            float ts  = ((float)i + 0.5f) * inv_n;
            float col = fmaf(ts, dx,   col0p);
            float row = fmaf(ts, drow, row0p);
            float cf = floorf(col), rf = floorf(row);
            float fc = col - cf,    fr = row - rf;
            unsigned off = (unsigned)(int)fmaf(rf, (float)QW, cf);
            float2 L  = vp[off];
            float2 Rr = vp[off + 1];
            acc += bil2(L, Rr, fc, fr);
        }
    }

    #pragma unroll
    for (int off = 32; off > 0; off >>= 1)
        acc += __shfl_down(acc, off, 64);

    if (lane == 0) out[ray] = acc * (seg * inv_n);
}

extern "C" void kernel_launch(void* const* d_in, const int* in_sizes, int n_in,
                              void* d_out, int out_size, void* d_ws, size_t ws_size,
                              hipStream_t stream) {
    const float* img = (const float*)d_in[0];
    float* out = (float*)d_out;
    float2* vp = (float2*)d_ws;                    // 528*528*8 B = 2.23 MB

    build_vpairs<<<(QW * QW + 255) / 256, 256, 0, stream>>>(img, vp);

    const int n_rays = N_ANGLES * N_DET;           // 12800, one wave each
    fanbeam_kernel<<<n_rays * 64 / 256, 256, 0, stream>>>(vp, out);
}

// Round 3
// 66.269 us; speedup vs baseline: 1.0847x; 1.0741x over previous
//
#include <hip/hip_runtime.h>
#include <hip/hip_fp16.h>
#include <math.h>

#define N_IMG 512
#define N_ANGLES 25
#define N_DET 512
#define DET_SPACING 3.0f
#define SRC_DIST 512.0f
#define DET_DIST 512.0f
#define N_SAMPLES 1024
#define PAD 8
#define QW 528            // padded grid side: r,c in [-8, 519]
#define NGC 132           // column groups of 4 (QW/4)

// ---------------------------------------------------------------------------
// ws: 2.23 MB zero-padded FP16 QUAD array, blocked 2(rows)x4(cols) quads per
// 64 B cache line.
//   quad16(R,C) = half{v(r,c), v(r,c+1), v(r+1,c), v(r+1,c+1)} packed in 8 B.
//   idx = ((R>>1)*NGC + (C>>2))*8 + (R&1)*4 + (C&3)
//   One line covers a 3x5-pixel footprint -> ~0.25 (row-ish rays) to ~0.5
//   (col-ish rays) unique lines/sample, vs 0.6 for the fp32 2x2 quad (R12)
//   and ~0.7 for the R2 vpair.  R0/R2 A/B showed fanbeam is insensitive to
//   gather INSTR count and L2 footprint -> remaining VMEM cost is TA
//   unique-line throughput, which this halves.  Bilinear is computed in fp32
//   on fp16-rounded corners: per-corner err <= 2^-11*|v|, random-walk
//   accumulation over ~360 samples -> absmax bump ~+0.01..0.03.
// ---------------------------------------------------------------------------

__device__ __forceinline__ int qidx16(int R, int C) {
    return (((R >> 1) * NGC + (C >> 2)) << 3) + ((R & 1) << 2) + (C & 3);
}

__device__ __forceinline__ float img_at(const float* __restrict__ img, int r, int c) {
    return ((unsigned)r < N_IMG && (unsigned)c < N_IMG) ? img[(r << 9) + c] : 0.0f;
}

__global__ __launch_bounds__(256) void build_quads16(const float* __restrict__ img,
                                                     uint2* __restrict__ quad) {
    int idx = blockIdx.x * 256 + (int)threadIdx.x;
    if (idx >= QW * QW) return;
    int R = idx / QW, C = idx - R * QW;
    int r = R - PAD, c = C - PAD;
    __half2 tp = __floats2half2_rn(img_at(img, r,     c), img_at(img, r,     c + 1));
    __half2 bt = __floats2half2_rn(img_at(img, r + 1, c), img_at(img, r + 1, c + 1));
    uint2 q;
    q.x = *reinterpret_cast<unsigned int*>(&tp);
    q.y = *reinterpret_cast<unsigned int*>(&bt);
    quad[qidx16(R, C)] = q;
}

// Clip [tlo,thi] to { t : lo <= v0 + t*dv <= hi }.
__device__ __forceinline__ void slab(float v0, float dv, float lo, float hi,
                                     float& tlo, float& thi) {
    if (fabsf(dv) < 1e-8f) {
        if (v0 < lo || v0 > hi) { tlo = 1.0f; thi = 0.0f; }
    } else {
        float inv = 1.0f / dv;
        float ta = (lo - v0) * inv;
        float tb = (hi - v0) * inv;
        tlo = fmaxf(tlo, fminf(ta, tb));
        thi = fminf(thi, fmaxf(ta, tb));
    }
}

__device__ __forceinline__ float bil16(uint2 q, float fc, float fr) {
    float2 top = __half22float2(*reinterpret_cast<__half2*>(&q.x));
    float2 bot = __half22float2(*reinterpret_cast<__half2*>(&q.y));
    float tv = fmaf(fc, top.y - top.x, top.x);
    float bv = fmaf(fc, bot.y - bot.x, bot.x);
    return fmaf(fr, bv - tv, tv);
}

// One wave per ray; 4-deep batched loads; clamp-free padded inner loop.
__global__ __launch_bounds__(256) void fanbeam_kernel(const uint2* __restrict__ quad,
                                                      float* __restrict__ out) {
    const int gid  = blockIdx.x * 256 + (int)threadIdx.x;
    const int ray  = gid >> 6;
    const int lane = (int)threadIdx.x & 63;
    if (ray >= N_ANGLES * N_DET) return;

    const int a = ray >> 9;
    const int d = ray & 511;

    float beta = (2.0f * (float)a / 25.0f) * 3.14159265358979323846f;
    float c, s;
    __sincosf(beta, &s, &c);
    float t = ((float)d - (N_DET - 1) * 0.5f) * DET_SPACING;
    float srcx = -SRC_DIST * s;
    float srcy =  SRC_DIST * c;
    float dx = (t * c + DET_DIST * s) - srcx;
    float dy = (t * s - DET_DIST * c) - srcy;
    float seg = sqrtf(dx * dx + dy * dy);

    const float half = (N_IMG - 1) * 0.5f;
    const float col0 = srcx + half;            // unpadded (for clipping)
    const float row0 = half - srcy;
    const float drow = -dy;
    const float col0p = col0 + (float)PAD;     // padded-coordinate origins
    const float row0p = row0 + (float)PAD;
    const float inv_n = 1.0f / N_SAMPLES;

    float tA = 0.0f, tB = 1.0f;
    slab(col0, dx,   -1.01f, 512.01f, tA, tB);
    slab(row0, drow, -1.01f, 512.01f, tA, tB);

    float acc = 0.0f;
    if (tA <= tB) {
        int i_lo = max(0,             (int)floorf(tA * N_SAMPLES - 0.5f) - 1);
        int i_hi = min(N_SAMPLES - 1, (int)ceilf (tB * N_SAMPLES - 0.5f) + 1);
        int n = i_hi - i_lo + 1;                       // wave-uniform
        int k = 0;
        // 4-deep batches: 4 independent dwordx2 gathers in flight; padded
        // coords are always >= ~5 within the window -> trunc == floor, no clamps.
        for (; k + 256 <= n; k += 256) {
            float f0 = (float)(i_lo + k + lane);       // exact in fp32
            float acc4 = 0.0f;
            #pragma unroll
            for (int j = 0; j < 4; ++j) {
                float ts  = (f0 + (64.0f * j + 0.5f)) * inv_n;
                float col = fmaf(ts, dx,   col0p);
                float row = fmaf(ts, drow, row0p);
                float cf = floorf(col), rf = floorf(row);
                float fc = col - cf,    fr = row - rf;
                uint2 q = quad[qidx16((int)rf, (int)cf)];
                acc4 += bil16(q, fc, fr);
            }
            acc += acc4;
        }
        // Tail (< 4 strides): plain loop, still clamp-free.
        #pragma unroll 2
        for (int i = i_lo + k + lane; i <= i_hi; i += 64) {
            float ts  = ((float)i + 0.5f) * inv_n;
            float col = fmaf(ts, dx,   col0p);
            float row = fmaf(ts, drow, row0p);
            float cf = floorf(col), rf = floorf(row);
            float fc = col - cf,    fr = row - rf;
            uint2 q = quad[qidx16((int)rf, (int)cf)];
            acc += bil16(q, fc, fr);
        }
    }

    #pragma unroll
    for (int off = 32; off > 0; off >>= 1)
        acc += __shfl_down(acc, off, 64);

    if (lane == 0) out[ray] = acc * (seg * inv_n);
}

extern "C" void kernel_launch(void* const* d_in, const int* in_sizes, int n_in,
                              void* d_out, int out_size, void* d_ws, size_t ws_size,
                              hipStream_t stream) {
    const float* img = (const float*)d_in[0];
    float* out = (float*)d_out;
    uint2* quad = (uint2*)d_ws;                    // 528*528*8 B = 2.23 MB

    build_quads16<<<(QW * QW + 255) / 256, 256, 0, stream>>>(img, quad);

    const int n_rays = N_ANGLES * N_DET;           // 12800, one wave each
    fanbeam_kernel<<<n_rays * 64 / 256, 256, 0, stream>>>(quad, out);
}